// Round 8
// baseline (77.233 us; speedup 1.0000x reference)
//
#include <hip/hip_runtime.h>
#include <hip/hip_bf16.h>

#define NN 64
#define CC 3
#define LL 4096
#define SS 64
#define KK 128
#define WW 4033           // LL - SS + 1
#define BLKN 8            // blocks per n (each covers 512 windows)

typedef __attribute__((ext_vector_type(8))) short v8s;   // 8 bf16 MFMA A/B frag
typedef __attribute__((ext_vector_type(4))) float v4f;   // 4 fp32 MFMA C/D frag

// ---- ws layout (bytes) ----
// d2g:  u32[NN*KK]        @ 0       (32768)
// cnt:  u32[NN]           @ 32768   (256)
// hs2g: f32[CC*KK]        @ 33024   (1536)   -0.5*||s||^2
// shb:  uint4[CC*1024]    @ 34560   (49152)  fragment-order bf16 shapelets
// hx2g: f32[NN*CC*4096]   @ 131072  (3.1 MB) -0.5*sliding||x_w||^2 (-1e30 pad)
#define WS_CNT_OFF 32768
#define WS_HS2_OFF 33024
#define WS_SHB_OFF 34560
#define WS_HX2_OFF 131072

__device__ __forceinline__ unsigned bf16_rne(float f) {
    unsigned u = __float_as_uint(f);
    return (u + 0x7FFFu + ((u >> 16) & 1u)) >> 16;
}

// ---------------------------------------------------------------------------
// Prep, grid 128: blocks 0..95 each build TWO (n,c) -0.5*x2 sliding tables
// (halves the dispatch count vs one-per-block); blocks 96..127 init/hs2/pack.
__global__ __launch_bounds__(256) void me_prep(
        const float* __restrict__ x,
        const float* __restrict__ shp,
        unsigned* __restrict__ d2g,
        unsigned* __restrict__ cnt,
        float* __restrict__ hs2g,
        uint4* __restrict__ shb,
        float* __restrict__ hx2g) {
    const int b = blockIdx.x, t = threadIdx.x;
    if (b < 96) {
        __shared__ float P[LL];      // inclusive prefix of x^2
        __shared__ float wtot[4];
        const int lane = t & 63, wave = t >> 6;
        const int base = t * 16;
        for (int s2 = 0; s2 < 2; ++s2) {
            const int id = 2 * b + s2;            // 0..191 = n*3 + c
            const int n = id / 3, c = id - n * 3;
            if (s2) __syncthreads();              // P reuse hazard
            const float* xc = x + ((size_t)n * CC + c) * LL;
            float q[16];
            {
                float4 A0 = *(const float4*)(xc + base);
                float4 A1 = *(const float4*)(xc + base + 4);
                float4 A2 = *(const float4*)(xc + base + 8);
                float4 A3 = *(const float4*)(xc + base + 12);
                q[0]=A0.x; q[1]=A0.y; q[2]=A0.z;  q[3]=A0.w;
                q[4]=A1.x; q[5]=A1.y; q[6]=A1.z;  q[7]=A1.w;
                q[8]=A2.x; q[9]=A2.y; q[10]=A2.z; q[11]=A2.w;
                q[12]=A3.x;q[13]=A3.y;q[14]=A3.z; q[15]=A3.w;
            }
            float run = 0.f;
            #pragma unroll
            for (int i = 0; i < 16; ++i) { run += q[i] * q[i]; q[i] = run; }
            float sc = run;
            #pragma unroll
            for (int d = 1; d < 64; d <<= 1) {
                float u = __shfl_up(sc, d, 64);
                if (lane >= d) sc += u;
            }
            if (lane == 63) wtot[wave] = sc;
            __syncthreads();
            float excl = sc - run;
            for (int w2 = 0; w2 < wave; ++w2) excl += wtot[w2];
            #pragma unroll
            for (int i = 0; i < 16; ++i) q[i] += excl;
            *(float4*)(P + base)      = make_float4(q[0], q[1], q[2], q[3]);
            *(float4*)(P + base + 4)  = make_float4(q[4], q[5], q[6], q[7]);
            *(float4*)(P + base + 8)  = make_float4(q[8], q[9], q[10], q[11]);
            *(float4*)(P + base + 12) = make_float4(q[12], q[13], q[14], q[15]);
            __syncthreads();
            float* dst = hx2g + ((size_t)n * CC + c) * LL;
            #pragma unroll
            for (int i = 0; i < 16; ++i) {
                int w = base + i;
                float o = -1e30f;                  // pad: windows >= WW masked
                if (w < WW) {
                    float I1 = P[w + 63];
                    float I0 = (w > 0) ? P[w - 1] : 0.f;
                    o = -0.5f * (I1 - I0);
                }
                dst[w] = o;
            }
        }
    } else {
        int tid = (b - 96) * 256 + t;
        if (tid < NN * KK) d2g[tid] = 0x7F800000u;     // +inf bits
        if (tid < NN) cnt[tid] = 0u;
        if (tid < CC * KK) {
            const float* r = shp + tid * SS;
            float a = 0.f;
            #pragma unroll 8
            for (int s = 0; s < SS; ++s) a += r[s] * r[s];
            hs2g[tid] = -0.5f * a;
        }
        if (tid < CC * 1024) {
            // B-operand frag order: chunk ((c*8+nt)*2+sc)*64+lane holds
            // shp[c][nt*16+(lane&15)][sc*32+(lane>>4)*8 + j], j=0..7 (RNE bf16)
            int c   = tid >> 10;
            int r   = tid & 1023;
            int nt  = r >> 7;
            int scb = (r >> 6) & 1;
            int l   = r & 63;
            int row  = nt * 16 + (l & 15);
            int koff = scb * 32 + (l >> 4) * 8;
            const float* s = shp + ((size_t)(c * KK + row)) * SS + koff;
            float4 f0 = *(const float4*)s;
            float4 f1 = *(const float4*)(s + 4);
            uint4 o;
            o.x = (bf16_rne(f0.y) << 16) | bf16_rne(f0.x);
            o.y = (bf16_rne(f0.w) << 16) | bf16_rne(f0.z);
            o.z = (bf16_rne(f1.y) << 16) | bf16_rne(f1.x);
            o.w = (bf16_rne(f1.w) << 16) | bf16_rne(f1.z);
            shb[tid] = o;
        }
    }
}

// ---------------------------------------------------------------------------
// Main: 512 blocks = (n, 512-window supertile). Staged ONCE -> ONE pre-MFMA
// barrier. Wave = 128 windows (8 m-tiles) x 128 shapelets (8 n-tiles),
// K=64 (2 chunks). B-frags reused across 8 m-tiles.
// acc init = -0.5*s2 (regs); epilogue adds precomputed -0.5*x2 (global table,
// -1e30 pads mask invalid windows). min d2 = max(-2*maxD, 0).
__global__ __launch_bounds__(256, 2) void me_main(
        const float* __restrict__ x,
        const ushort* __restrict__ shb_g,
        const float* __restrict__ hs2g,
        const float* __restrict__ hx2g,
        unsigned* __restrict__ d2g,
        unsigned* __restrict__ cnt,
        float* __restrict__ out) {

    __shared__ __align__(16) ushort shb[CC * 8192];   // 48 KB shapelet frags
    __shared__ __align__(8) ushort xs2[2][CC][640];   // [copy][c] bf16 x (575 used)
    __shared__ unsigned red[KK];
    __shared__ int lastflag;

    const int b    = blockIdx.x;
    const int n    = b >> 3;          // BLKN=8 blocks per n
    const int tg   = b & 7;
    const int w0   = tg * 512;
    const int t    = threadIdx.x;
    const int lane = t & 63, wave = t >> 6;
    const int quad = lane >> 4, col = lane & 15;
    const int wbase = wave * 128;     // wave's window base within supertile

    if (t < KK) red[t] = 0x7F800000u;

    // ---- DMA all shapelet frags global(ws) -> LDS, once per block ----
    {
        typedef __attribute__((address_space(1))) const uint4 gu4;
        typedef __attribute__((address_space(3))) uint4 lu4;
        const uint4* gbase = (const uint4*)shb_g;
        #pragma unroll
        for (int it = 0; it < 12; ++it) {
            const uint4* gp = gbase + it * 256 + t;                 // per-lane
            uint4* lp = (uint4*)shb + (it * 256 + wave * 64);       // wave-uniform
            __builtin_amdgcn_global_load_lds((gu4*)gp, (lu4*)lp, 16, 0, 0);
        }
    }

    // ---- -0.5*s2 into registers (indexed by this lane's col) ----
    float hsv[CC][8];
    #pragma unroll
    for (int c = 0; c < CC; ++c)
        #pragma unroll
        for (int nt = 0; nt < 8; ++nt)
            hsv[c][nt] = hs2g[c * KK + nt * 16 + col];

    const float* xb   = x + (size_t)n * (CC * LL);
    const float* hx2b = hx2g + (size_t)n * (CC * LL);

    // ---- stage 512+63 x elems per channel, bf16 dual-copy (once) ----
    #pragma unroll
    for (int it = 0; it < 2; ++it) {
        int e = t + it * 256;
        if (e < 432) {                       // 144 float4 per channel
            int c = e / 144, qd = e - c * 144;
            int idx = qd * 4, gi = w0 + idx;
            float4 v;
            if (gi + 3 < LL) v = *(const float4*)(xb + c * LL + gi);
            else {
                v.x = (gi     < LL) ? xb[c * LL + gi]     : 0.f;
                v.y = (gi + 1 < LL) ? xb[c * LL + gi + 1] : 0.f;
                v.z = (gi + 2 < LL) ? xb[c * LL + gi + 2] : 0.f;
                v.w = (gi + 3 < LL) ? xb[c * LL + gi + 3] : 0.f;
            }
            unsigned h0 = bf16_rne(v.x), h1 = bf16_rne(v.y);
            unsigned h2 = bf16_rne(v.z), h3 = bf16_rne(v.w);
            uint2 p0; p0.x = h0 | (h1 << 16); p0.y = h2 | (h3 << 16);
            *(uint2*)&xs2[0][c][idx] = p0;                 // copy0: x[i]
            if (idx > 0) xs2[1][c][idx - 1] = (ushort)h0;  // copy1: x[i+1]
            *(uint*)&xs2[1][c][idx] = h1 | (h2 << 16);
            xs2[1][c][idx + 2] = (ushort)h3;
        }
    }
    __syncthreads();   // the ONLY pre-MFMA barrier (also drains the DMA)

    float rmax[8];
    #pragma unroll
    for (int nt = 0; nt < 8; ++nt) rmax[nt] = -3.4e38f;

    #pragma unroll
    for (int c = 0; c < CC; ++c) {
        // -0.5*x2 for this wave's 128 window rows (global, L2-resident)
        const float* hp = hx2b + c * LL + w0 + wbase + quad * 4;
        v4f hxv[8];
        #pragma unroll
        for (int mt = 0; mt < 8; ++mt) hxv[mt] = *(const v4f*)(hp + mt * 16);
        // A-frags: 8 m-tiles x 2 k-chunks, dual-copy dword-aligned reads
        v8s af[8][2];
        #pragma unroll
        for (int mt = 0; mt < 8; ++mt)
            #pragma unroll
            for (int sc = 0; sc < 2; ++sc) {
                int e0 = wbase + mt * 16 + col + sc * 32 + quad * 8;
                int p  = col & 1;
                const uint* ap = (const uint*)&xs2[p][c][e0 - p];
                union { v8s v; uint u[4]; } au;
                au.u[0] = ap[0]; au.u[1] = ap[1];
                au.u[2] = ap[2]; au.u[3] = ap[3];
                af[mt][sc] = au.v;
            }
        // 4 groups of 2 n-tiles to bound acc register pressure
        #pragma unroll
        for (int g = 0; g < 4; ++g) {
            v4f acc[2][8];   // [nt2][mt]
            #pragma unroll
            for (int nt2 = 0; nt2 < 2; ++nt2) {
                float h = hsv[c][g * 2 + nt2];
                v4f a = {h, h, h, h};
                #pragma unroll
                for (int mt = 0; mt < 8; ++mt) acc[nt2][mt] = a;
            }
            #pragma unroll
            for (int sc = 0; sc < 2; ++sc)
                #pragma unroll
                for (int nt2 = 0; nt2 < 2; ++nt2) {
                    int nt = g * 2 + nt2;
                    v8s bfr = *(const v8s*)(shb + (((c * 8 + nt) * 2 + sc) * 64 + lane) * 8);
                    #pragma unroll
                    for (int mt = 0; mt < 8; ++mt)
                        acc[nt2][mt] = __builtin_amdgcn_mfma_f32_16x16x32_bf16(
                            af[mt][sc], bfr, acc[nt2][mt], 0, 0, 0);
                }
            // epilogue: add -0.5*x2 rows, fold max over 32 window rows
            #pragma unroll
            for (int nt2 = 0; nt2 < 2; ++nt2) {
                float m = -3.4e38f;
                #pragma unroll
                for (int mt = 0; mt < 8; ++mt) {
                    v4f a = acc[nt2][mt];
                    #pragma unroll
                    for (int r = 0; r < 4; ++r)
                        m = fmaxf(m, a[r] + hxv[mt][r]);
                }
                rmax[g * 2 + nt2] = fmaxf(rmax[g * 2 + nt2], m);
            }
        }
    }

    // ---- reduce over quads (window rows live across quad+regs) ----
    #pragma unroll
    for (int nt = 0; nt < 8; ++nt) {
        float v = rmax[nt];
        v = fmaxf(v, __shfl_xor(v, 16, 64));
        v = fmaxf(v, __shfl_xor(v, 32, 64));
        rmax[nt] = v;
    }
    if (quad == 0) {
        #pragma unroll
        for (int nt = 0; nt < 8; ++nt) {
            float d2 = fmaxf(-2.f * rmax[nt], 0.f);
            atomicMin(&red[nt * 16 + col], __float_as_uint(d2));
        }
    }
    __syncthreads();
    if (t < KK) atomicMin(&d2g[n * KK + t], red[t]);   // device-scope RMW

    // ---- last block for this n writes sqrt -> out ----
    __syncthreads();   // vmcnt(0) drain: d2g mins globally done before cnt
    if (t == 0) {
        unsigned old = atomicAdd(&cnt[n], 1u);
        lastflag = (old == BLKN - 1) ? 1 : 0;
    }
    __syncthreads();
    if (lastflag && t < KK) {
        unsigned bits = atomicMin(&d2g[n * KK + t], 0x7F800000u);
        out[n * KK + t] = sqrtf(__uint_as_float(bits));
    }
}

// ---------------------------------------------------------------------------
extern "C" void kernel_launch(void* const* d_in, const int* in_sizes, int n_in,
                              void* d_out, int out_size, void* d_ws, size_t ws_size,
                              hipStream_t stream) {
    const float* x   = (const float*)d_in[0];   // (N, C, L) fp32
    const float* shp = (const float*)d_in[1];   // (C, K, S) fp32
    unsigned* d2g  = (unsigned*)d_ws;
    unsigned* cnt  = (unsigned*)((char*)d_ws + WS_CNT_OFF);
    float*    hs2g = (float*)((char*)d_ws + WS_HS2_OFF);
    uint4*    shb  = (uint4*)((char*)d_ws + WS_SHB_OFF);
    float*    hx2g = (float*)((char*)d_ws + WS_HX2_OFF);
    float* out = (float*)d_out;

    hipLaunchKernelGGL(me_prep, dim3(128), dim3(256), 0, stream,
                       x, shp, d2g, cnt, hs2g, shb, hx2g);
    hipLaunchKernelGGL(me_main, dim3(NN * BLKN), dim3(256), 0, stream,
                       x, (const ushort*)shb, hs2g, hx2g, d2g, cnt, out);
}